// Round 19
// baseline (28.271 us; speedup 1.0000x reference)
//
#include <hip/hip_runtime.h>

#define G 32
#define G2 (G*G)
#define G3 (G*G*G)
#define NPTS 50000
#define NB 8
#define NC 16
#define NSLAB 4                       // slabs per batch, 8 x-planes each
#define SLABP 8                       // planes per slab
#define KR 8                          // point-ranges per (batch,slab)
#define PPR (NPTS/KR)                 // 6250 points per range
#define CELLS (SLABP*G2)              // 8192 cells per slab

// ws: part u64[NB*NSLAB][KR][CELLS] = 16 MB, nothing pre-zeroed.
// Packed cell accumulator: [63:57]=sum(fr) [56:38]=x [37:19]=y [18:0]=z,
// each addend (rint(d*2048)+2048)*fr <= 8192; per-block per-cell sum(fr)
// stays far below 127 (block sees 1/8 of one batch) -> no cross-field carry.
#define OFF_PART 0

// K1: one block per (batch, slab, range). Direct scan of x (no payload
// round-trip); ONE packed u64 LDS atomic per corner-hit; dense partial out.
__global__ __launch_bounds__(1024) void ge_slab(const float* __restrict__ x,
                                                unsigned long long* __restrict__ part) {
    __shared__ unsigned long long A[CELLS];   // 64 KB
    const int tid  = threadIdx.x;
    const int k    = blockIdx.x;      // 0..KR-1
    const int slab = blockIdx.y;      // 0..NSLAB-1
    const int b    = blockIdx.z;      // 0..NB-1

    #pragma unroll
    for (int i = 0; i < CELLS / 1024; ++i) A[i * 1024 + tid] = 0ull;
    __syncthreads();

    const float* xb = x + (size_t)b * 3 * NPTS;
    const int n0 = k * PPR, n1 = n0 + PPR;

    for (int n = n0 + tid; n < n1; n += 1024) {
        float rx = (xb[n]          + 0.5f) * 32.0f - 0.5f;
        int p1 = (int)fminf(fmaxf(floorf(rx), 0.0f), 31.0f);
        int p2 = (int)fminf(fmaxf(ceilf (rx), 0.0f), 31.0f);
        bool in1 = (p1 >> 3) == slab, in2 = (p2 >> 3) == slab;
        if (!in1 && !in2) continue;

        float ry = (xb[NPTS + n]   + 0.5f) * 32.0f - 0.5f;
        float rz = (xb[2*NPTS + n] + 0.5f) * 32.0f - 0.5f;
        float fy1 = fminf(fmaxf(floorf(ry), 0.0f), 31.0f);
        float fy2 = fminf(fmaxf(ceilf (ry), 0.0f), 31.0f);
        float fz1 = fminf(fmaxf(floorf(rz), 0.0f), 31.0f);
        float fz2 = fminf(fmaxf(ceilf (rz), 0.0f), 31.0f);
        float dy1 = ry - fy1, dy2 = ry - fy2;
        float dz1 = rz - fz1, dz2 = rz - fz2;

        // unscaled biased addends (scaled by fr per x-corner below)
        unsigned uy1 = (unsigned)((int)rintf(dy1 * 2048.0f) + 2048);
        unsigned uy2 = (unsigned)((int)rintf(dy2 * 2048.0f) + 2048);
        unsigned uz1 = (unsigned)((int)rintf(dz1 * 2048.0f) + 2048);
        unsigned uz2 = (unsigned)((int)rintf(dz2 * 2048.0f) + 2048);
        unsigned fr1 = (p1 == p2) ? 2u : 1u;   // ref double-counts collapsed x-corner

        #pragma unroll
        for (int v = 0; v < 2; ++v) {
            int xp = v ? p2 : p1;
            unsigned fri = v ? 1u : fr1;
            bool go = (v == 0 || p2 != p1) && ((xp >> 3) == slab);
            if (go) {
                float dx = rx - (float)xp;
                float dx2 = dx * dx;
                unsigned ax = (unsigned)((int)rintf(dx * 2048.0f) + 2048) * fri;
                unsigned long long base = ((unsigned long long)fri << 57)
                                        | ((unsigned long long)ax  << 38);
                int lpbase = (xp & 7) * G2;
                #pragma unroll
                for (int cy = 0; cy < 2; ++cy) {
                    float dy = cy ? dy2 : dy1;
                    float iy = cy ? fy2 : fy1;
                    unsigned ay = (cy ? uy2 : uy1) * fri;
                    float dxy2 = dx2 + dy * dy;
                    #pragma unroll
                    for (int cz = 0; cz < 2; ++cz) {
                        float dz = cz ? dz2 : dz1;
                        float d2 = dxy2 + dz * dz;
                        if (d2 < 0.7569f) {     // 0.87^2, full-fp32 gate
                            float iz = cz ? fz2 : fz1;
                            unsigned az = (cz ? uz2 : uz1) * fri;
                            int cell = lpbase + (int)iy * G + (int)iz;
                            atomicAdd(&A[cell],
                                      base | ((unsigned long long)ay << 19)
                                           | (unsigned long long)az);
                        }
                    }
                }
            }
        }
    }
    __syncthreads();

    unsigned long long* pp = part + ((size_t)(b * NSLAB + slab) * KR + k) * CELLS;
    #pragma unroll
    for (int i = 0; i < CELLS / 1024; ++i)
        pp[i * 1024 + tid] = A[i * 1024 + tid];
}

// K2: one block per (batch, slab, plane-in-slab); decode+sum KR partials in
// fp32, then fused 16-channel epilogue.
__global__ __launch_bounds__(1024) void ge_reduce(const unsigned long long* __restrict__ part,
                                                  const float* __restrict__ W,
                                                  const float* __restrict__ bias,
                                                  float* __restrict__ out) {
    const int tid = threadIdx.x;
    const int g  = blockIdx.x >> 3;      // (b*NSLAB+slab) 0..31
    const int lp = blockIdx.x & 7;       // plane within slab
    const int b = g >> 2, slab = g & 3;

    float cw = 0.f, fxs = 0.f, fys = 0.f, fzs = 0.f;
    const unsigned long long* pg = part + (size_t)g * KR * CELLS + lp * G2 + tid;
    #pragma unroll
    for (int r = 0; r < KR; ++r) {
        unsigned long long a = pg[(size_t)r * CELLS];
        cw  += (float)(unsigned)(a >> 57);
        fxs += (float)(unsigned)((a >> 38) & 0x7FFFFull);
        fys += (float)(unsigned)((a >> 19) & 0x7FFFFull);
        fzs += (float)(unsigned)( a         & 0x7FFFFull);
    }
    const float kq = 1.0f / 2048.0f;
    const float sx = (fxs - 2048.0f * cw) * kq;
    const float sy = (fys - 2048.0f * cw) * kq;
    const float sz = (fzs - 2048.0f * cw) * kq;
    const float inv = 1.0f / fmaxf(cw, 1.0f);

    const int s = slab * SLABP + lp;
    float* ob = out + (size_t)b * NC * G3 + (size_t)s * G2 + tid;
    #pragma unroll
    for (int ch = 0; ch < NC; ++ch) {
        float v = W[ch * 3 + 0] * sx + W[ch * 3 + 1] * sy + W[ch * 3 + 2] * sz
                + cw * bias[ch];
        ob[(size_t)ch * G3] = v * inv;
    }
}

// ---------- fallback: round-7 single kernel (used if ws too small) ----------
#define SEG 12288
#define QMAX SEG
__global__ __launch_bounds__(1024) void ge_fused(const float* __restrict__ x,
                                                 const float* __restrict__ W,
                                                 const float* __restrict__ bias,
                                                 float* __restrict__ out) {
    __shared__ float acc[G2][4];
    __shared__ int   q[QMAX];
    __shared__ int   qcount;
    const int b = blockIdx.x >> 5;
    const int s = blockIdx.x & 31;
    const float fs = (float)s;
    const int lane = threadIdx.x & 63;
    for (int i = threadIdx.x; i < G2 * 4; i += 1024) ((float*)acc)[i] = 0.0f;
    if (threadIdx.x == 0) qcount = 0;
    __syncthreads();
    const float* xb = x + (size_t)b * 3 * NPTS;
    for (int seg = 0; seg < NPTS; seg += SEG) {
        const int seg_end = (seg + SEG < NPTS) ? seg + SEG : NPTS;
        for (int base = seg; base < seg_end; base += 1024) {
            int n = base + threadIdx.x;
            bool pred = false; int tag = 0;
            if (n < seg_end) {
                float rx = (xb[n] + 0.5f) * 32.0f - 0.5f;
                int p1 = (int)fminf(fmaxf(floorf(rx), 0.0f), 31.0f);
                int p2 = (int)fminf(fmaxf(ceilf (rx), 0.0f), 31.0f);
                int reps = (p1 == s) + (p2 == s);
                pred = reps > 0;
                tag = n | (reps == 2 ? (int)0x80000000 : 0);
            }
            unsigned long long mask = __ballot(pred);
            int wcnt = __popcll(mask);
            if (wcnt) {
                int wbase = 0;
                if (lane == 0) wbase = atomicAdd(&qcount, wcnt);
                wbase = __shfl(wbase, 0);
                if (pred) q[wbase + __popcll(mask & ((1ULL << lane) - 1ULL))] = tag;
            }
        }
        __syncthreads();
        const int cnt = qcount;
        for (int i = threadIdx.x; i < cnt; i += 1024) {
            int e = q[i];
            int n = e & 0x7fffffff;
            float fr = (e < 0) ? 2.0f : 1.0f;
            float rx = (xb[n]          + 0.5f) * 32.0f - 0.5f;
            float ry = (xb[NPTS + n]   + 0.5f) * 32.0f - 0.5f;
            float rz = (xb[2*NPTS + n] + 0.5f) * 32.0f - 0.5f;
            float dx = rx - fs;
            float fy1 = fminf(fmaxf(floorf(ry), 0.0f), 31.0f);
            float fy2 = fminf(fmaxf(ceilf (ry), 0.0f), 31.0f);
            float fz1 = fminf(fmaxf(floorf(rz), 0.0f), 31.0f);
            float fz2 = fminf(fmaxf(ceilf (rz), 0.0f), 31.0f);
            #pragma unroll
            for (int cy = 0; cy < 2; ++cy) {
                float iy = cy ? fy2 : fy1;
                float dy = ry - iy;
                #pragma unroll
                for (int cz = 0; cz < 2; ++cz) {
                    float iz = cz ? fz2 : fz1;
                    float dz = rz - iz;
                    float d2 = dx * dx + dy * dy + dz * dz;
                    if (d2 < 0.7569f) {
                        int cell = (int)iy * G + (int)iz;
                        atomicAdd(&acc[cell][0], fr * dx);
                        atomicAdd(&acc[cell][1], fr * dy);
                        atomicAdd(&acc[cell][2], fr * dz);
                        atomicAdd(&acc[cell][3], fr);
                    }
                }
            }
        }
        __syncthreads();
        if (threadIdx.x == 0) qcount = 0;
        __syncthreads();
    }
    int cell = threadIdx.x;
    float sx = acc[cell][0], sy = acc[cell][1], sz = acc[cell][2], cnt = acc[cell][3];
    float inv = 1.0f / fmaxf(cnt, 1.0f);
    float* ob = out + (size_t)b * NC * G3 + (size_t)s * G2 + cell;
    #pragma unroll
    for (int c = 0; c < NC; ++c) {
        float v = W[c * 3 + 0] * sx + W[c * 3 + 1] * sy + W[c * 3 + 2] * sz
                + cnt * bias[c];
        ob[(size_t)c * G3] = v * inv;
    }
}

extern "C" void kernel_launch(void* const* d_in, const int* in_sizes, int n_in,
                              void* d_out, int out_size, void* d_ws, size_t ws_size,
                              hipStream_t stream) {
    const float* x    = (const float*)d_in[0];   // [8,3,50000]
    const float* W    = (const float*)d_in[1];   // [16,3]
    const float* bias = (const float*)d_in[2];   // [16]
    float* out = (float*)d_out;                  // [8,16,32,32,32]

    const size_t need = (size_t)NB * NSLAB * KR * CELLS * sizeof(unsigned long long);
    if (ws_size >= need) {
        unsigned long long* part = (unsigned long long*)((char*)d_ws + OFF_PART);
        ge_slab  <<<dim3(KR, NSLAB, NB), 1024, 0, stream>>>(x, part);
        ge_reduce<<<NB * NSLAB * SLABP, 1024, 0, stream>>>(part, W, bias, out);
    } else {
        ge_fused<<<NB * G, 1024, 0, stream>>>(x, W, bias, out);
    }
}

// Round 20
// 19.239 us; speedup vs baseline: 1.4695x; 1.4695x over previous
//
#include <hip/hip_runtime.h>

#define G 32
#define G2 (G*G)
#define G3 (G*G*G)
#define NPTS 50000
#define NB 8
#define NC 16
#define NCHUNK_PER_B 49              // ceil(50000/1024)
#define NCHUNK (NB*NCHUNK_PER_B)     // 392
#define SUBCAP 1024                  // max entries per (chunk,plane): <=1 per point

// ws layout (bytes) — nothing needs pre-zeroing, no global atomics anywhere:
//   [0, 50176)    hist[392][32] (int)
//   [65536, ...)  payload u64[392][32][1024]  (98 MiB, sparsely touched)
#define OFF_HIST    0
#define OFF_PAYLOAD 65536

// 8-byte payload entry, fully corner-resolved in bin:
//   [55:43] ax   biased x-residual addend rint(dx*2048)+2048      (13b)
//   [42:30] ay1  biased y-residual addend for corner y1           (13b)
//   [29:17] az1  biased z-residual addend for corner z1           (13b)
//   [16:12] iy1  floor-clamped y cell                             (5b)
//   [11:7]  iz1  floor-clamped z cell                             (5b)
//   [6]     sy   iy2-iy1 (0/1)    [5] sz   iz2-iz1 (0/1)
//   [4]     fr-1 (x-collapse double count)
//   [3:0]   mask fp32-exact d^2<0.87^2 gate for (cy,cz)=(0,0),(0,1),(1,0),(1,1)
// ay2 = ay1 - 2048*sy exactly (rint distributes over integer shift); az2 likewise.

// K1: bin one 1024-point chunk; compute corners+gates here; plane-grouped LDS
// staging; coalesced 8B copy-out. Entries with mask==0 are pruned.
__global__ __launch_bounds__(1024) void ge_bin(const float* __restrict__ x,
                                               int* __restrict__ hist,
                                               unsigned long long* __restrict__ payload) {
    __shared__ unsigned long long sp[2048];   // 16 KB staged entries
    __shared__ unsigned char spl[2048];       // plane of each staged entry
    __shared__ int h[G];
    __shared__ int offs[G + 1];

    const int tid = threadIdx.x;
    const int b   = blockIdx.y;
    const int c   = b * NCHUNK_PER_B + blockIdx.x;
    const int n   = blockIdx.x * 1024 + tid;
    const bool valid = n < NPTS;

    if (tid < G) h[tid] = 0;
    __syncthreads();

    unsigned long long e1 = 0, e2 = 0;
    int p1 = 0, p2 = 0, r1 = 0, r2 = 0;
    bool put1 = false, put2 = false;

    if (valid) {
        const float* xb = x + (size_t)b * 3 * NPTS;
        float rx = (xb[n]          + 0.5f) * 32.0f - 0.5f;
        float ry = (xb[NPTS + n]   + 0.5f) * 32.0f - 0.5f;
        float rz = (xb[2*NPTS + n] + 0.5f) * 32.0f - 0.5f;
        p1 = (int)fminf(fmaxf(floorf(rx), 0.0f), 31.0f);
        p2 = (int)fminf(fmaxf(ceilf (rx), 0.0f), 31.0f);

        float fy1 = fminf(fmaxf(floorf(ry), 0.0f), 31.0f);
        float fy2 = fminf(fmaxf(ceilf (ry), 0.0f), 31.0f);
        float fz1 = fminf(fmaxf(floorf(rz), 0.0f), 31.0f);
        float fz2 = fminf(fmaxf(ceilf (rz), 0.0f), 31.0f);
        float dy1 = ry - fy1, dy2 = ry - fy2;
        float dz1 = rz - fz1, dz2 = rz - fz2;
        float dy1s = dy1 * dy1, dy2s = dy2 * dy2;
        float dz1s = dz1 * dz1, dz2s = dz2 * dz2;

        int iy1 = (int)fy1, sy = (int)fy2 - iy1;
        int iz1 = (int)fz1, sz = (int)fz2 - iz1;
        int ay1 = (int)rintf(dy1 * 2048.0f) + 2048;
        int az1 = (int)rintf(dz1 * 2048.0f) + 2048;
        unsigned long long common =
              ((unsigned long long)(unsigned)ay1 << 30)
            | ((unsigned long long)(unsigned)az1 << 17)
            | ((unsigned long long)(unsigned)iy1 << 12)
            | ((unsigned long long)(unsigned)iz1 << 7)
            | ((unsigned long long)(unsigned)sy  << 6)
            | ((unsigned long long)(unsigned)sz  << 5);
        unsigned fr1 = (p1 == p2) ? 2u : 1u;  // ref double-counts collapsed x

        {   // plane p1 entry
            float dx = rx - (float)p1;
            float dx2 = dx * dx;
            float a0 = dx2 + dy1s, a1 = dx2 + dy2s;
            unsigned m = 0;
            if (a0 + dz1s < 0.7569f) m |= 1u;
            if (a0 + dz2s < 0.7569f) m |= 2u;
            if (a1 + dz1s < 0.7569f) m |= 4u;
            if (a1 + dz2s < 0.7569f) m |= 8u;
            if (m) {
                unsigned ax = (unsigned)((int)rintf(dx * 2048.0f) + 2048);
                e1 = ((unsigned long long)ax << 43) | common
                   | ((unsigned long long)(fr1 - 1u) << 4) | m;
                put1 = true;
                r1 = atomicAdd(&h[p1], 1);
            }
        }
        if (p2 != p1) {  // plane p2 entry
            float dx = rx - (float)p2;
            float dx2 = dx * dx;
            float a0 = dx2 + dy1s, a1 = dx2 + dy2s;
            unsigned m = 0;
            if (a0 + dz1s < 0.7569f) m |= 1u;
            if (a0 + dz2s < 0.7569f) m |= 2u;
            if (a1 + dz1s < 0.7569f) m |= 4u;
            if (a1 + dz2s < 0.7569f) m |= 8u;
            if (m) {
                unsigned ax = (unsigned)((int)rintf(dx * 2048.0f) + 2048);
                e2 = ((unsigned long long)ax << 43) | common | m;  // fr=1
                put2 = true;
                r2 = atomicAdd(&h[p2], 1);
            }
        }
    }
    __syncthreads();

    if (tid == 0) {
        int run = 0;
        #pragma unroll
        for (int p = 0; p < G; ++p) { offs[p] = run; run += h[p]; }
        offs[G] = run;
    }
    __syncthreads();

    if (put1) {
        int i1 = offs[p1] + r1;
        sp[i1] = e1; spl[i1] = (unsigned char)p1;
    }
    if (put2) {
        int i2 = offs[p2] + r2;
        sp[i2] = e2; spl[i2] = (unsigned char)p2;
    }
    if (tid < G) hist[c * G + tid] = h[tid];
    __syncthreads();

    const int T = offs[G];
    unsigned long long* chunk_pl = payload + (size_t)c * G * SUBCAP;
    for (int e = tid; e < T; e += 1024) {
        int p = spl[e];
        chunk_pl[(size_t)p * SUBCAP + (e - offs[p])] = sp[e];
    }
}

// K2: pure-integer decode + masked packed u64 LDS atomics (1 per corner-hit).
// Accumulator fields: [63:57]=sum(fr) [56:38]=x [37:19]=y [18:0]=z.
__global__ __launch_bounds__(1024) void ge_accum(const unsigned long long* __restrict__ payload,
                                                 const int* __restrict__ hist,
                                                 const float* __restrict__ W,
                                                 const float* __restrict__ bias,
                                                 float* __restrict__ out) {
    __shared__ unsigned long long A[G2];   // 8 KB
    const int tid = threadIdx.x;
    const int b = blockIdx.x >> 5;
    const int s = blockIdx.x & 31;

    A[tid] = 0ull;
    __syncthreads();

    const int wave = tid >> 6, lane = tid & 63;
    for (int blk = wave; blk < NCHUNK_PER_B; blk += 16) {
        const int cc = b * NCHUNK_PER_B + blk;
        const int ec = hist[cc * G + s];
        const unsigned long long* q = payload + ((size_t)cc * G + s) * SUBCAP;
        for (int i = lane; i < ec; i += 64) {
            unsigned long long e = q[i];
            unsigned m   = (unsigned)e & 15u;
            unsigned fr  = 1u + (((unsigned)e >> 4) & 1u);
            int sz  = ((int)e >> 5) & 1;
            int sy  = ((int)e >> 6) & 1;
            int iz1 = ((int)e >> 7) & 31;
            int iy1 = ((int)e >> 12) & 31;
            unsigned az1 = (unsigned)(e >> 17) & 0x1FFFu;
            unsigned ay1 = (unsigned)(e >> 30) & 0x1FFFu;
            unsigned ax  = (unsigned)(e >> 43) & 0x1FFFu;

            unsigned long long base = ((unsigned long long)fr << 57)
                                    | ((unsigned long long)(ax * fr) << 38);
            unsigned ayl = ay1 * fr, ayh = (ay1 - 2048u * sy) * fr;
            unsigned azl = az1 * fr, azh = (az1 - 2048u * sz) * fr;
            int cell = iy1 * G + iz1;

            if (m & 1u) atomicAdd(&A[cell],
                ((unsigned long long)ayl << 19) | azl | base);
            if (m & 2u) atomicAdd(&A[cell + sz],
                ((unsigned long long)ayl << 19) | azh | base);
            if (m & 4u) atomicAdd(&A[cell + G * sy],
                ((unsigned long long)ayh << 19) | azl | base);
            if (m & 8u) atomicAdd(&A[cell + G * sy + sz],
                ((unsigned long long)ayh << 19) | azh | base);
        }
    }
    __syncthreads();

    const unsigned long long a = A[tid];
    const float cw  = (float)(unsigned)(a >> 57);
    const float fxs = (float)(unsigned)((a >> 38) & 0x7FFFFull);
    const float fys = (float)(unsigned)((a >> 19) & 0x7FFFFull);
    const float fzs = (float)(unsigned)( a         & 0x7FFFFull);
    const float kq = 1.0f / 2048.0f;
    const float sx = (fxs - 2048.0f * cw) * kq;
    const float sy = (fys - 2048.0f * cw) * kq;
    const float sz = (fzs - 2048.0f * cw) * kq;
    const float inv = 1.0f / fmaxf(cw, 1.0f);

    float* ob = out + (size_t)b * NC * G3 + (size_t)s * G2 + tid;
    #pragma unroll
    for (int ch = 0; ch < NC; ++ch) {
        float v = W[ch * 3 + 0] * sx + W[ch * 3 + 1] * sy + W[ch * 3 + 2] * sz
                + cw * bias[ch];
        ob[(size_t)ch * G3] = v * inv;
    }
}

// ---------- fallback: round-7 single kernel (used if ws too small) ----------
#define SEG 12288
#define QMAX SEG
__global__ __launch_bounds__(1024) void ge_fused(const float* __restrict__ x,
                                                 const float* __restrict__ W,
                                                 const float* __restrict__ bias,
                                                 float* __restrict__ out) {
    __shared__ float acc[G2][4];
    __shared__ int   q[QMAX];
    __shared__ int   qcount;
    const int b = blockIdx.x >> 5;
    const int s = blockIdx.x & 31;
    const float fs = (float)s;
    const int lane = threadIdx.x & 63;
    for (int i = threadIdx.x; i < G2 * 4; i += 1024) ((float*)acc)[i] = 0.0f;
    if (threadIdx.x == 0) qcount = 0;
    __syncthreads();
    const float* xb = x + (size_t)b * 3 * NPTS;
    for (int seg = 0; seg < NPTS; seg += SEG) {
        const int seg_end = (seg + SEG < NPTS) ? seg + SEG : NPTS;
        for (int base = seg; base < seg_end; base += 1024) {
            int n = base + threadIdx.x;
            bool pred = false; int tag = 0;
            if (n < seg_end) {
                float rx = (xb[n] + 0.5f) * 32.0f - 0.5f;
                int p1 = (int)fminf(fmaxf(floorf(rx), 0.0f), 31.0f);
                int p2 = (int)fminf(fmaxf(ceilf (rx), 0.0f), 31.0f);
                int reps = (p1 == s) + (p2 == s);
                pred = reps > 0;
                tag = n | (reps == 2 ? (int)0x80000000 : 0);
            }
            unsigned long long mask = __ballot(pred);
            int wcnt = __popcll(mask);
            if (wcnt) {
                int wbase = 0;
                if (lane == 0) wbase = atomicAdd(&qcount, wcnt);
                wbase = __shfl(wbase, 0);
                if (pred) q[wbase + __popcll(mask & ((1ULL << lane) - 1ULL))] = tag;
            }
        }
        __syncthreads();
        const int cnt = qcount;
        for (int i = threadIdx.x; i < cnt; i += 1024) {
            int e = q[i];
            int n = e & 0x7fffffff;
            float fr = (e < 0) ? 2.0f : 1.0f;
            float rx = (xb[n]          + 0.5f) * 32.0f - 0.5f;
            float ry = (xb[NPTS + n]   + 0.5f) * 32.0f - 0.5f;
            float rz = (xb[2*NPTS + n] + 0.5f) * 32.0f - 0.5f;
            float dx = rx - fs;
            float fy1 = fminf(fmaxf(floorf(ry), 0.0f), 31.0f);
            float fy2 = fminf(fmaxf(ceilf (ry), 0.0f), 31.0f);
            float fz1 = fminf(fmaxf(floorf(rz), 0.0f), 31.0f);
            float fz2 = fminf(fmaxf(ceilf (rz), 0.0f), 31.0f);
            #pragma unroll
            for (int cy = 0; cy < 2; ++cy) {
                float iy = cy ? fy2 : fy1;
                float dy = ry - iy;
                #pragma unroll
                for (int cz = 0; cz < 2; ++cz) {
                    float iz = cz ? fz2 : fz1;
                    float dz = rz - iz;
                    float d2 = dx * dx + dy * dy + dz * dz;
                    if (d2 < 0.7569f) {
                        int cell = (int)iy * G + (int)iz;
                        atomicAdd(&acc[cell][0], fr * dx);
                        atomicAdd(&acc[cell][1], fr * dy);
                        atomicAdd(&acc[cell][2], fr * dz);
                        atomicAdd(&acc[cell][3], fr);
                    }
                }
            }
        }
        __syncthreads();
        if (threadIdx.x == 0) qcount = 0;
        __syncthreads();
    }
    int cell = threadIdx.x;
    float sx = acc[cell][0], sy = acc[cell][1], sz = acc[cell][2], cnt = acc[cell][3];
    float inv = 1.0f / fmaxf(cnt, 1.0f);
    float* ob = out + (size_t)b * NC * G3 + (size_t)s * G2 + cell;
    #pragma unroll
    for (int c = 0; c < NC; ++c) {
        float v = W[c * 3 + 0] * sx + W[c * 3 + 1] * sy + W[c * 3 + 2] * sz
                + cnt * bias[c];
        ob[(size_t)c * G3] = v * inv;
    }
}

extern "C" void kernel_launch(void* const* d_in, const int* in_sizes, int n_in,
                              void* d_out, int out_size, void* d_ws, size_t ws_size,
                              hipStream_t stream) {
    const float* x    = (const float*)d_in[0];   // [8,3,50000]
    const float* W    = (const float*)d_in[1];   // [16,3]
    const float* bias = (const float*)d_in[2];   // [16]
    float* out = (float*)d_out;                  // [8,16,32,32,32]

    const size_t need = OFF_PAYLOAD
                      + (size_t)NCHUNK * G * SUBCAP * sizeof(unsigned long long);
    if (ws_size >= need) {
        char* wsb = (char*)d_ws;
        int* hist = (int*)(wsb + OFF_HIST);
        unsigned long long* payload = (unsigned long long*)(wsb + OFF_PAYLOAD);

        ge_bin  <<<dim3(NCHUNK_PER_B, NB), 1024, 0, stream>>>(x, hist, payload);
        ge_accum<<<NB * G, 1024, 0, stream>>>(payload, hist, W, bias, out);
    } else {
        ge_fused<<<NB * G, 1024, 0, stream>>>(x, W, bias, out);
    }
}